// Round 14
// baseline (131.507 us; speedup 1.0000x reference)
//
#include <hip/hip_runtime.h>
#include <stdint.h>

#define LL 2048
#define EE 1024
#define HH 16
#define DD 64
#define KX 1056   // 1024 + 16 (Sp*Mabs) + 16 (s*Mrel)

using short8 = __attribute__((ext_vector_type(8))) short;
using s4v    = __attribute__((ext_vector_type(4))) short;
using f32x4  = __attribute__((ext_vector_type(4))) float;

#if __has_builtin(__builtin_amdgcn_mfma_f32_16x16x16_bf16)
#define MFMA16(a,b,c) __builtin_amdgcn_mfma_f32_16x16x16_bf16(a,b,c,0,0,0)
#elif __has_builtin(__builtin_amdgcn_mfma_f32_16x16x16bf16_1k)
#define MFMA16(a,b,c) __builtin_amdgcn_mfma_f32_16x16x16bf16_1k(a,b,c,0,0,0)
#else
static __device__ __forceinline__ f32x4 mfma16f(s4v a, s4v b, f32x4 c) {
  asm volatile("v_mfma_f32_16x16x16_bf16 %0, %1, %2, %0" : "+v"(c) : "v"(a), "v"(b));
  return c;
}
#define MFMA16(a,b,c) mfma16f(a,b,c)
#endif

__device__ __forceinline__ short f2bf(float x) {
  union { float f; uint32_t u; } v; v.f = x;
  uint32_t r = v.u + 0x7fffu + ((v.u >> 16) & 1u);
  return (short)(r >> 16);
}
__device__ __forceinline__ float bf2f(short s) {
  union { uint32_t u; float f; } v; v.u = ((uint32_t)(uint16_t)s) << 16;
  return v.f;
}

// async global->LDS, 16 B per lane; lds base wave-uniform, global src per-lane
__device__ __forceinline__ void gld16(short* lds, const short* g) {
  __builtin_amdgcn_global_load_lds(
      (const __attribute__((address_space(1))) unsigned int*)g,
      (__attribute__((address_space(3))) unsigned int*)lds, 16, 0, 0);
}

// ---- fused: bf16 converts (blocks < NB_CONV) + uker + mrelker tails ----
#define NB_CONV 10240
__global__ __launch_bounds__(256) void convfused(
    const float* __restrict__ Q, const float* __restrict__ K,
    const float* __restrict__ V, const float* __restrict__ Wq,
    const float* __restrict__ Wk, const float* __restrict__ Wv,
    const float* __restrict__ Wout,
    const float* __restrict__ wka, const float* __restrict__ wkr,
    const float* __restrict__ wva, const float* __restrict__ wvr,
    short* __restrict__ Qb, short* __restrict__ Kb, short* __restrict__ Vb,
    short* __restrict__ Wqb, short* __restrict__ Wkb, short* __restrict__ Wvb,
    short* __restrict__ W2, float* __restrict__ u) {
  int b = blockIdx.x;
  if (b < NB_CONV) {
    const int S1 = LL * EE / 4;
    const int SW = EE * EE / 4;
    int i4 = b * 256 + threadIdx.x;
    const float* src; short* dst; int idx4; bool strided = false;
    if (i4 < 3 * S1) {
      int z = i4 >> 19; idx4 = i4 & (S1 - 1);
      src = z == 0 ? Q : (z == 1 ? K : V);
      dst = z == 0 ? Qb : (z == 1 ? Kb : Vb);
    } else {
      int j = i4 - 3 * S1;
      int z = j >> 18; idx4 = j & (SW - 1);
      src = z == 0 ? Wq : (z == 1 ? Wk : (z == 2 ? Wv : Wout));
      dst = z == 0 ? Wqb : (z == 1 ? Wkb : (z == 2 ? Wvb : W2));
      strided = (z == 3);
    }
    int i = idx4 * 4;
    const float4 v = *(const float4*)(src + i);
    int di = strided ? ((i >> 10) * KX + (i & 1023)) : i;
    union { short s[4]; uint64_t u; } p;
    p.s[0] = f2bf(v.x); p.s[1] = f2bf(v.y); p.s[2] = f2bf(v.z); p.s[3] = f2bf(v.w);
    *(uint64_t*)(dst + di) = p.u;
  } else if (b < NB_CONV + 128) {
    int flat = (b - NB_CONV) * 256 + threadIdx.x;
    int c = flat & (EE - 1);
    int h = (flat >> 10) & (HH - 1);
    int s = flat >> 14;
    const float* w = s ? wkr : wka;
    float acc = 0.f;
    #pragma unroll 8
    for (int d = 0; d < DD; ++d)
      acc += Wq[(size_t)(h * DD + d) * EE + c] * w[h * DD + d];
    u[flat] = acc;
  } else {
    int flat = (b - NB_CONV - 128) * 256 + threadIdx.x;
    int n = flat >> 5;
    int s = (flat >> 4) & 1;
    int h = flat & 15;
    const float* w = s ? wvr : wva;
    float acc = 0.f;
    #pragma unroll 8
    for (int d = 0; d < DD; ++d)
      acc += Wout[(size_t)n * EE + h * DD + d] * w[h * DD + d];
    W2[(size_t)n * KX + 1024 + s * 16 + h] = f2bf(acc);
  }
}

// ---- fused proj GEMM (blocks 0..767, 64x128 tiles) + qawker (768..768+2047) ----
// GEMM gld16 double-buffered, 1 barrier/step. z==2 stores C^T via swizzled LDS.
__global__ __launch_bounds__(256, 2) void projqaw(
    const short* __restrict__ Aall, const short* __restrict__ Ball,
    short* __restrict__ Call,
    int K, int aBatch, int bBatch, int cBatch,
    int ldc, int vTransZ, int ldcT, int scaleZ, float scaleVal,
    const float* __restrict__ Qf, const float* __restrict__ u,
    float* __restrict__ qaw)
{
  __shared__ __align__(16) short smem[12288];   // As[2][2048] | Bs[2][4096]
  int b = blockIdx.x;
  int t = threadIdx.x;

  if (b >= 768) {
    // ---- qawker branch: one q-row per block ----
    int i = b - 768;
    int h = t >> 4, seg = t & 15;
    const float* u0 = u + (size_t)h * EE;
    const float* u1 = u + (size_t)HH * EE + (size_t)h * EE;
    const float* q = Qf + (size_t)i * EE;
    float a0 = 0.f, a1 = 0.f;
    for (int cc = 0; cc < 64; ++cc) {
      int c = cc * 16 + seg;
      float qv = q[c];
      a0 += qv * u0[c];
      a1 += qv * u1[c];
    }
    #pragma unroll
    for (int m = 1; m < 16; m <<= 1) {
      a0 += __shfl_xor(a0, m);
      a1 += __shfl_xor(a1, m);
    }
    if (seg == 0) { qaw[i * 32 + h] = a0; qaw[i * 32 + 16 + h] = a1; }
    return;
  }

  // ---- GEMM branch: 64(m) x 128(n) tile ----
  short* As0 = smem;          // [2][2048]
  short* Bs0 = smem + 4096;   // [2][4096]
  int z = b / 256;
  int rem = b % 256;
  int n0 = (rem & 7) * 128, m0 = (rem >> 3) * 64;
  const short* A = Aall + (size_t)z * aBatch;
  const short* B = Ball + (size_t)z * bBatch;
  int lane = t & 63, w = t >> 6;
  int wm = w >> 1, wn = w & 1;
  int fr = lane & 15, g = lane >> 4, fo = g * 8;
  int lr = lane >> 2, lc = (lane & 3) * 8;
  const f32x4 vzero = {0.f, 0.f, 0.f, 0.f};
  f32x4 acc[2][4];
  #pragma unroll
  for (int i = 0; i < 2; ++i)
    #pragma unroll
    for (int j = 0; j < 4; ++j) acc[i][j] = vzero;

  int kTiles = K / 32;
  {
    int arow = w * 16 + lr;
    gld16(&As0[w * 512], A + (size_t)(m0 + arow) * K + lc);
    #pragma unroll
    for (int c = 0; c < 2; ++c) {
      int brow = (w * 2 + c) * 16 + lr;
      gld16(&Bs0[(w * 2 + c) * 512], B + (size_t)(n0 + brow) * K + lc);
    }
  }
  int cur = 0;
  for (int kt = 0; kt < kTiles; ++kt) {
    __syncthreads();
    if (kt + 1 < kTiles) {
      int arow = w * 16 + lr;
      gld16(&As0[(cur ^ 1) * 2048 + w * 512],
            A + (size_t)(m0 + arow) * K + (kt + 1) * 32 + lc);
      #pragma unroll
      for (int c = 0; c < 2; ++c) {
        int brow = (w * 2 + c) * 16 + lr;
        gld16(&Bs0[(cur ^ 1) * 4096 + (w * 2 + c) * 512],
              B + (size_t)(n0 + brow) * K + (kt + 1) * 32 + lc);
      }
    }
    short8 af[2], bf[4];
    #pragma unroll
    for (int i = 0; i < 2; ++i)
      af[i] = *(const short8*)&As0[cur * 2048 + (wm * 32 + i * 16 + fr) * 32 + fo];
    #pragma unroll
    for (int j = 0; j < 4; ++j)
      bf[j] = *(const short8*)&Bs0[cur * 4096 + (wn * 64 + j * 16 + fr) * 32 + fo];
    #pragma unroll
    for (int i = 0; i < 2; ++i)
      #pragma unroll
      for (int j = 0; j < 4; ++j)
        acc[i][j] = __builtin_amdgcn_mfma_f32_16x16x32_bf16(af[i], bf[j], acc[i][j], 0, 0, 0);
    cur ^= 1;
  }

  short* C = Call + (size_t)z * cBatch;
  bool doScale = (z == scaleZ);

  if (z == vTransZ) {
    // C^T via swizzled LDS transpose: tile is 128 rows (n) x 64 cols (m) of C^T
    __syncthreads();
    #pragma unroll
    for (int i = 0; i < 2; ++i) {
      #pragma unroll
      for (int j = 0; j < 4; ++j) {
        int nl = wn * 64 + j * 16 + fr;        // 0..127
        int mc = wm * 8 + i * 4 + g;           // m/4 chunk, 0..15
        union { short s[4]; uint64_t u; } pk;
        #pragma unroll
        for (int r = 0; r < 4; ++r) {
          float val = acc[i][j][r];
          if (doScale) val *= scaleVal;
          pk.s[r] = f2bf(val);
        }
        *(uint64_t*)&smem[nl * 64 + ((mc ^ (nl & 15)) * 4)] = pk.u;
      }
    }
    __syncthreads();
    int row = t >> 1, seg = t & 1;             // 128 rows, 2 segs of 32 m-cols
    #pragma unroll
    for (int cc = 0; cc < 4; ++cc) {
      int c8 = seg * 8 + cc * 2;               // 8B-chunk index, 0..15
      uint64_t lo = *(uint64_t*)&smem[row * 64 + ((c8       ^ (row & 15)) * 4)];
      uint64_t hi = *(uint64_t*)&smem[row * 64 + (((c8 + 1) ^ (row & 15)) * 4)];
      union { uint64_t q[2]; int4 v; } st; st.q[0] = lo; st.q[1] = hi;
      *(int4*)(C + (size_t)(n0 + row) * ldcT + m0 + c8 * 4) = st.v;
    }
    return;
  }

  int rb = (lane >> 4) * 4;
  #pragma unroll
  for (int i = 0; i < 2; ++i) {
    #pragma unroll
    for (int j = 0; j < 4; ++j) {
      int n = n0 + wn * 64 + j * 16 + fr;
      #pragma unroll
      for (int r = 0; r < 4; ++r) {
        int m = m0 + wm * 32 + i * 16 + rb + r;
        float val = acc[i][j][r];
        if (doScale) val *= scaleVal;
        C[(size_t)m * ldc + n] = f2bf(val);
      }
    }
  }
}

// ---- final GEMM: 64x64 tile (512 blocks), gld16 dbuf, fp32 out + bias ----
__global__ __launch_bounds__(256, 4) void gemm_bt(
    const short* __restrict__ A, const short* __restrict__ B,
    float* __restrict__ C, int K, int ldc, const float* __restrict__ bias)
{
  __shared__ __align__(16) short As[2][64 * 32];
  __shared__ __align__(16) short Bs[2][64 * 32];
  int m0 = blockIdx.y * 64, n0 = blockIdx.x * 64;
  int t = threadIdx.x;
  int lane = t & 63, w = t >> 6;
  int wm = w >> 1, wn = w & 1;
  int fr = lane & 15, fo = (lane >> 4) * 8;
  int lr = lane >> 2, lc = (lane & 3) * 8;
  const f32x4 vzero = {0.f, 0.f, 0.f, 0.f};
  f32x4 acc[2][2];
  #pragma unroll
  for (int i = 0; i < 2; ++i)
    #pragma unroll
    for (int j = 0; j < 2; ++j) acc[i][j] = vzero;

  int kTiles = K / 32;
  {
    int row = w * 16 + lr;
    gld16(&As[0][w * 512], A + (size_t)(m0 + row) * K + lc);
    gld16(&Bs[0][w * 512], B + (size_t)(n0 + row) * K + lc);
  }
  int cur = 0;
  for (int kt = 0; kt < kTiles; ++kt) {
    __syncthreads();
    if (kt + 1 < kTiles) {
      int row = w * 16 + lr;
      gld16(&As[cur ^ 1][w * 512], A + (size_t)(m0 + row) * K + (kt + 1) * 32 + lc);
      gld16(&Bs[cur ^ 1][w * 512], B + (size_t)(n0 + row) * K + (kt + 1) * 32 + lc);
    }
    short8 af[2], bfr[2];
    #pragma unroll
    for (int i = 0; i < 2; ++i)
      af[i] = *(const short8*)&As[cur][(wm * 32 + i * 16 + fr) * 32 + fo];
    #pragma unroll
    for (int j = 0; j < 2; ++j)
      bfr[j] = *(const short8*)&Bs[cur][(wn * 32 + j * 16 + fr) * 32 + fo];
    #pragma unroll
    for (int i = 0; i < 2; ++i)
      #pragma unroll
      for (int j = 0; j < 2; ++j)
        acc[i][j] = __builtin_amdgcn_mfma_f32_16x16x32_bf16(af[i], bfr[j], acc[i][j], 0, 0, 0);
    cur ^= 1;
  }

  int rb = (lane >> 4) * 4;
  #pragma unroll
  for (int i = 0; i < 2; ++i) {
    #pragma unroll
    for (int j = 0; j < 2; ++j) {
      int n = n0 + wn * 32 + j * 16 + fr;
      float bv = bias[n];
      #pragma unroll
      for (int r = 0; r < 4; ++r) {
        int m = m0 + wm * 32 + i * 16 + rb + r;
        C[(size_t)m * ldc + n] = acc[i][j][r] + bv;
      }
    }
  }
}

// ---- flash v10: split-K(2), gld_lds dbuf + XOR swizzle, 1 barrier/tile ----
__global__ __launch_bounds__(256, 4) void flash10(
    const short* __restrict__ qp, const short* __restrict__ kp,
    const short* __restrict__ vpT, const float* __restrict__ qaw,
    short* __restrict__ Obf, float* __restrict__ stats)
{
  __shared__ __align__(16) short lds[16384];
  int h = blockIdx.y;
  int q0 = blockIdx.x * 64;
  int split = blockIdx.z;
  int kbeg = split * 1024;
  int t = threadIdx.x, w = t >> 6, lane = t & 63;
  int g = lane >> 4, fr = lane & 15;
  int gi = q0 + w * 16 + fr;
  float gif = (float)gi;
  float g4f = (float)(4 * g);
  const f32x4 vzero = {0.f, 0.f, 0.f, 0.f};

  int srow = lane >> 3;
  int schunk = (lane & 7) ^ srow;
  const short* ksrcA = kp + (size_t)(w * 16 + srow) * EE + h * 64 + schunk * 8;
  const short* ksrcB = ksrcA + (size_t)8 * EE;
  const short* vsrcA = vpT + (size_t)(h * 64 + w * 16 + srow) * LL + kbeg + schunk * 8;
  const short* vsrcB = vsrcA + (size_t)8 * LL;

  int fx = fr & 7;
  int kA0 = fr * 64 + ((g ^ fx) * 8);
  int kA1 = fr * 64 + (((g | 4) ^ fx) * 8);
  int g2 = g >> 1, gh = (g & 1) * 4;
  int vA[4];
  #pragma unroll
  for (int jt = 0; jt < 4; ++jt)
    vA[jt] = fr * 64 + (((2 * jt + g2) ^ fx) * 8) + gh;

  short8 qf[2];
  #pragma unroll
  for (int ks = 0; ks < 2; ++ks)
    qf[ks] = *(const short8*)(qp + (size_t)gi * EE + h * 64 + ks * 32 + g * 8);

  const float LOG2E = 1.4426950408889634f;
  const float sc = LOG2E / 32.f;
  float qa_s = qaw[gi * 32 + h] * sc;
  float qw_s = qaw[gi * 32 + 16 + h] * (sc / 5000.f);
  float qapw = qa_s + qw_s, qamw = qa_s - qw_s;

  float m2 = -1e30f, lsum = 0.f, SpA = 0.f, SrA = 0.f;
  f32x4 Oa[4];
  #pragma unroll
  for (int fc = 0; fc < 4; ++fc) Oa[fc] = vzero;

  {
    short* kb = lds;
    short* vb = lds + 4096;
    gld16(kb + w * 1024,       ksrcA + (size_t)kbeg * EE);
    gld16(kb + w * 1024 + 512, ksrcB + (size_t)kbeg * EE);
    gld16(vb + w * 1024,       vsrcA);
    gld16(vb + w * 1024 + 512, vsrcB);
  }

  int cur = 0;
  for (int kt = 0; kt < 16; ++kt) {
    int k0 = kbeg + kt * 64;
    float k0f = (float)k0;
    __syncthreads();

    if (kt < 15) {
      short* kb2 = lds + (cur ^ 1) * 8192;
      short* vb2 = kb2 + 4096;
      gld16(kb2 + w * 1024,       ksrcA + (size_t)(k0 + 64) * EE);
      gld16(kb2 + w * 1024 + 512, ksrcB + (size_t)(k0 + 64) * EE);
      gld16(vb2 + w * 1024,       vsrcA + (kt + 1) * 64);
      gld16(vb2 + w * 1024 + 512, vsrcB + (kt + 1) * 64);
    }
    const short* kb = lds + cur * 8192;
    const short* vb = kb + 4096;

    f32x4 St[4];
    #pragma unroll
    for (int jt = 0; jt < 4; ++jt) {
      f32x4 a = vzero;
      a = __builtin_amdgcn_mfma_f32_16x16x32_bf16(
              *(const short8*)(kb + jt * 1024 + kA0), qf[0], a, 0, 0, 0);
      a = __builtin_amdgcn_mfma_f32_16x16x32_bf16(
              *(const short8*)(kb + jt * 1024 + kA1), qf[1], a, 0, 0, 0);
      St[jt] = a;
    }

    float pf[4][4];
    float tmv = -1e30f;
    if (k0 < q0) {
      float b4 = fmaf(g4f, qamw, k0f * qa_s + (gif - k0f) * qw_s);
      #pragma unroll
      for (int jt = 0; jt < 4; ++jt)
        #pragma unroll
        for (int r = 0; r < 4; ++r) {
          float e = St[jt][r] + fmaf((float)(jt * 16 + r), qamw, b4);
          pf[jt][r] = e;
          tmv = fmaxf(tmv, e);
        }
    } else if (k0 > q0) {
      float b4 = fmaf(g4f, qapw, k0f * qa_s + (k0f - gif) * qw_s);
      #pragma unroll
      for (int jt = 0; jt < 4; ++jt)
        #pragma unroll
        for (int r = 0; r < 4; ++r) {
          float e = St[jt][r] + fmaf((float)(jt * 16 + r), qapw, b4);
          pf[jt][r] = e;
          tmv = fmaxf(tmv, e);
        }
    } else {
      #pragma unroll
      for (int jt = 0; jt < 4; ++jt)
        #pragma unroll
        for (int r = 0; r < 4; ++r) {
          float jgf = k0f + g4f + (float)(jt * 16 + r);
          float e = St[jt][r] + jgf * qa_s + fabsf(gif - jgf) * qw_s;
          pf[jt][r] = e;
          tmv = fmaxf(tmv, e);
        }
    }
    tmv = fmaxf(tmv, __shfl_xor(tmv, 16));
    tmv = fmaxf(tmv, __shfl_xor(tmv, 32));

    if (__any(tmv > m2 + 8.f)) {
      float mn = fmaxf(m2, tmv);
      float alpha = exp2f(m2 - mn);
      m2 = mn;
      lsum *= alpha; SpA *= alpha; SrA *= alpha;
      #pragma unroll
      for (int r = 0; r < 4; ++r) {
        float alr = __shfl(alpha, ((lane >> 4) << 2) + r);
        #pragma unroll
        for (int fc = 0; fc < 4; ++fc) Oa[fc][r] *= alr;
      }
    }

    float Pt = 0.f, S1 = 0.f;
    #pragma unroll
    for (int jt = 0; jt < 4; ++jt)
      #pragma unroll
      for (int r = 0; r < 4; ++r) {
        float p = exp2f(pf[jt][r] - m2);
        pf[jt][r] = p;
        Pt += p;
        S1 = fmaf(p, (float)(jt * 16 + r), S1);
      }
    float jbase = k0f + g4f;
    lsum += Pt;
    SpA += fmaf(jbase, Pt, S1);
    if (k0 > q0)       SrA += fmaf(jbase - gif, Pt, S1);
    else if (k0 < q0)  SrA -= fmaf(jbase - gif, Pt, S1);
    else {
      #pragma unroll
      for (int jt = 0; jt < 4; ++jt)
        #pragma unroll
        for (int r = 0; r < 4; ++r)
          SrA = fmaf(pf[jt][r], fabsf(gif - (jbase + (float)(jt * 16 + r))), SrA);
    }

    s4v pa[4];
    #pragma unroll
    for (int jt = 0; jt < 4; ++jt) {
      int lo, hi;
      asm("v_cvt_pk_bf16_f32 %0, %1, %2" : "=v"(lo) : "v"(pf[jt][0]), "v"(pf[jt][1]));
      asm("v_cvt_pk_bf16_f32 %0, %1, %2" : "=v"(hi) : "v"(pf[jt][2]), "v"(pf[jt][3]));
      union { int i[2]; s4v s; } uu; uu.i[0] = lo; uu.i[1] = hi;
      pa[jt] = uu.s;
    }

    #pragma unroll
    for (int jt = 0; jt < 4; ++jt) {
      #pragma unroll
      for (int fc = 0; fc < 4; ++fc) {
        s4v vv = *(const s4v*)(vb + fc * 1024 + vA[jt]);
        Oa[fc] = MFMA16(pa[jt], vv, Oa[fc]);
      }
    }
    cur ^= 1;
  }

  lsum += __shfl_xor(lsum, 16); lsum += __shfl_xor(lsum, 32);
  SpA  += __shfl_xor(SpA, 16);  SpA  += __shfl_xor(SpA, 32);
  SrA  += __shfl_xor(SrA, 16);  SrA  += __shfl_xor(SrA, 32);

  size_t sb = (size_t)(split * HH + h) * LL;
  if (g == 0) {
    float4 s4 = {m2, lsum, SpA, SrA};
    *(float4*)&stats[(sb + q0 + w * 16 + fr) * 4] = s4;
  }

  float linv = 1.f / lsum;
  #pragma unroll
  for (int r = 0; r < 4; ++r) {
    int q = q0 + w * 16 + 4 * g + r;
    float il = __shfl(linv, 4 * g + r);
    union { short s[4]; uint64_t u; } pk;
    #pragma unroll
    for (int fc = 0; fc < 4; ++fc) pk.s[fc] = f2bf(Oa[fc][r] * il);
    *(uint64_t*)&Obf[(sb + q) * 64 + fr * 4] = pk.u;
  }
}

// ---- merge 2 splits (permuted Obf reads), emit X2 ----
__global__ __launch_bounds__(256) void merge2(const short* __restrict__ Obf,
                                              const float* __restrict__ stats,
                                              short* __restrict__ X2) {
  int q = blockIdx.x;
  int t = threadIdx.x;
  int h = t >> 4, ds = (t & 15) * 4;
  float4 s[2];
  #pragma unroll
  for (int i = 0; i < 2; ++i)
    s[i] = *(const float4*)&stats[((size_t)(i * HH + h) * LL + q) * 4];
  float m = fmaxf(s[0].x, s[1].x);
  float a[2], denom = 0.f;
  #pragma unroll
  for (int i = 0; i < 2; ++i) { a[i] = exp2f(s[i].x - m); denom += a[i] * s[i].y; }
  float invd = 1.f / denom;
  float acc[4] = {0.f, 0.f, 0.f, 0.f};
  #pragma unroll
  for (int i = 0; i < 2; ++i) {
    float wgt = a[i] * s[i].y * invd;
    const short* ob = &Obf[((size_t)(i * HH + h) * LL + q) * 64];
    #pragma unroll
    for (int e = 0; e < 4; ++e) {
      int d = ds + e;
      int pidx = (d & 15) * 4 + (d >> 4);
      acc[e] = fmaf(wgt, bf2f(ob[pidx]), acc[e]);
    }
  }
  union { short s[4]; uint64_t u; } pk;
  #pragma unroll
  for (int e = 0; e < 4; ++e) pk.s[e] = f2bf(acc[e]);
  *(uint64_t*)&X2[(size_t)q * KX + h * 64 + ds] = pk.u;

  if (t < 32) {
    int hh = t & 15;
    float4 ts[2];
    float mm = -1e30f;
    #pragma unroll
    for (int i = 0; i < 2; ++i) {
      ts[i] = *(const float4*)&stats[((size_t)(i * HH + hh) * LL + q) * 4];
      mm = fmaxf(mm, ts[i].x);
    }
    float num = 0.f, den = 0.f;
    #pragma unroll
    for (int i = 0; i < 2; ++i) {
      float ai = exp2f(ts[i].x - mm);
      den += ai * ts[i].y;
      num += ai * ((t < 16) ? ts[i].z : ts[i].w);
    }
    float val = num / den;
    if (t >= 16) val *= (1.f / 5000.f);
    X2[(size_t)q * KX + 1024 + (t < 16 ? hh : 16 + hh)] = f2bf(val);
  }
}

extern "C" void kernel_launch(void* const* d_in, const int* in_sizes, int n_in,
                              void* d_out, int out_size, void* d_ws, size_t ws_size,
                              hipStream_t stream) {
  const float* V    = (const float*)d_in[0];
  const float* Kin  = (const float*)d_in[1];
  const float* Q    = (const float*)d_in[2];
  const float* Wq   = (const float*)d_in[4];
  const float* Wk   = (const float*)d_in[5];
  const float* Wv   = (const float*)d_in[6];
  const float* Wkr  = (const float*)d_in[7];
  const float* Wvr  = (const float*)d_in[8];
  const float* Wka  = (const float*)d_in[9];
  const float* Wva  = (const float*)d_in[10];
  const float* Wout = (const float*)d_in[11];
  const float* bout = (const float*)d_in[12];

  char* ws = (char*)d_ws;
  size_t off = 0;
  auto alloc = [&](size_t bytes) -> void* {
    void* p = ws + off;
    off = (off + bytes + 255) & ~(size_t)255;
    return p;
  };
  short* Qb  = (short*)alloc((size_t)LL * EE * 2);   // ┐ overlay (18.87 MB):
  short* Kb  = (short*)alloc((size_t)LL * EE * 2);   // │ dead after proj gemm;
  short* Vb  = (short*)alloc((size_t)LL * EE * 2);   // │ reused as Obf(8MB)+stats(1MB)
  short* Wqb = (short*)alloc((size_t)EE * EE * 2);   // │
  short* Wkb = (short*)alloc((size_t)EE * EE * 2);   // │
  short* Wvb = (short*)alloc((size_t)EE * EE * 2);   // ┘
  short* qp  = (short*)alloc((size_t)LL * EE * 2);
  short* kp  = (short*)alloc((size_t)LL * EE * 2);
  short* vpT = (short*)alloc((size_t)EE * LL * 2);
  short* W2  = (short*)alloc((size_t)EE * KX * 2);
  short* X2  = (short*)alloc((size_t)LL * KX * 2);
  float* u   = (float*)alloc((size_t)2 * HH * EE * 4);
  float* qaw = (float*)alloc((size_t)LL * 32 * 4);
  short* Obf   = Qb;                                             // 8,388,608 B
  float* stats = (float*)((char*)Qb + (size_t)16777216);         // 1,048,576 B
  (void)in_sizes; (void)n_in; (void)out_size; (void)ws_size;

  const float sc = 1.4426950408889634f / 32.f;

  // 1) bf16 converts + uker + mrelker, one launch
  convfused<<<NB_CONV + 256, 256, 0, stream>>>(
      Q, Kin, V, Wq, Wk, Wv, Wout, Wka, Wkr, Wva, Wvr,
      Qb, Kb, Vb, Wqb, Wkb, Wvb, W2, u);

  // 2) fused projections (64x128 tiles, 768 blocks) + qaw (2048 blocks)
  projqaw<<<768 + LL, 256, 0, stream>>>(Qb, Wqb, qp, EE,
                                        LL * EE, EE * EE, LL * EE,
                                        EE, /*vTransZ=*/2, /*ldcT=*/LL,
                                        /*scaleZ=*/0, sc,
                                        Q, u, qaw);

  // 3) split-K(2) flash (gld_lds dbuf + swizzle) -> bf16 partials + stats
  flash10<<<dim3(LL / 64, HH, 2), 256, 0, stream>>>(qp, kp, vpT, qaw, Obf, stats);

  // 4) merge 2 splits -> X2
  merge2<<<LL, 256, 0, stream>>>(Obf, stats, X2);

  // 5) final: d_out = X2 @ W2^T + b_out (64x64 tiles -> 512 blocks)
  dim3 go(EE / 64, LL / 64);
  gemm_bt<<<go, 256, 0, stream>>>(X2, W2, (float*)d_out, KX, EE, bout);
}

// Round 15
// 124.536 us; speedup vs baseline: 1.0560x; 1.0560x over previous
//
#include <hip/hip_runtime.h>
#include <stdint.h>

#define LL 2048
#define EE 1024
#define HH 16
#define DD 64
#define KX 1056   // 1024 + 16 (Sp*Mabs) + 16 (s*Mrel)

using short8 = __attribute__((ext_vector_type(8))) short;
using s4v    = __attribute__((ext_vector_type(4))) short;
using f32x4  = __attribute__((ext_vector_type(4))) float;

#if __has_builtin(__builtin_amdgcn_mfma_f32_16x16x16_bf16)
#define MFMA16(a,b,c) __builtin_amdgcn_mfma_f32_16x16x16_bf16(a,b,c,0,0,0)
#elif __has_builtin(__builtin_amdgcn_mfma_f32_16x16x16bf16_1k)
#define MFMA16(a,b,c) __builtin_amdgcn_mfma_f32_16x16x16bf16_1k(a,b,c,0,0,0)
#else
static __device__ __forceinline__ f32x4 mfma16f(s4v a, s4v b, f32x4 c) {
  asm volatile("v_mfma_f32_16x16x16_bf16 %0, %1, %2, %0" : "+v"(c) : "v"(a), "v"(b));
  return c;
}
#define MFMA16(a,b,c) mfma16f(a,b,c)
#endif

#define EXP2 __builtin_amdgcn_exp2f   // raw v_exp_f32; args bounded in flash

__device__ __forceinline__ short f2bf(float x) {
  union { float f; uint32_t u; } v; v.f = x;
  uint32_t r = v.u + 0x7fffu + ((v.u >> 16) & 1u);
  return (short)(r >> 16);
}
__device__ __forceinline__ float bf2f(short s) {
  union { uint32_t u; float f; } v; v.u = ((uint32_t)(uint16_t)s) << 16;
  return v.f;
}

// async global->LDS, 16 B per lane; lds base wave-uniform, global src per-lane
__device__ __forceinline__ void gld16(short* lds, const short* g) {
  __builtin_amdgcn_global_load_lds(
      (const __attribute__((address_space(1))) unsigned int*)g,
      (__attribute__((address_space(3))) unsigned int*)lds, 16, 0, 0);
}

// ---- fused: bf16 converts (blocks < NB_CONV) + uker + mrelker tails ----
#define NB_CONV 10240
__global__ __launch_bounds__(256) void convfused(
    const float* __restrict__ Q, const float* __restrict__ K,
    const float* __restrict__ V, const float* __restrict__ Wq,
    const float* __restrict__ Wk, const float* __restrict__ Wv,
    const float* __restrict__ Wout,
    const float* __restrict__ wka, const float* __restrict__ wkr,
    const float* __restrict__ wva, const float* __restrict__ wvr,
    short* __restrict__ Qb, short* __restrict__ Kb, short* __restrict__ Vb,
    short* __restrict__ Wqb, short* __restrict__ Wkb, short* __restrict__ Wvb,
    short* __restrict__ W2, float* __restrict__ u) {
  int b = blockIdx.x;
  if (b < NB_CONV) {
    const int S1 = LL * EE / 4;
    const int SW = EE * EE / 4;
    int i4 = b * 256 + threadIdx.x;
    const float* src; short* dst; int idx4; bool strided = false;
    if (i4 < 3 * S1) {
      int z = i4 >> 19; idx4 = i4 & (S1 - 1);
      src = z == 0 ? Q : (z == 1 ? K : V);
      dst = z == 0 ? Qb : (z == 1 ? Kb : Vb);
    } else {
      int j = i4 - 3 * S1;
      int z = j >> 18; idx4 = j & (SW - 1);
      src = z == 0 ? Wq : (z == 1 ? Wk : (z == 2 ? Wv : Wout));
      dst = z == 0 ? Wqb : (z == 1 ? Wkb : (z == 2 ? Wvb : W2));
      strided = (z == 3);
    }
    int i = idx4 * 4;
    const float4 v = *(const float4*)(src + i);
    int di = strided ? ((i >> 10) * KX + (i & 1023)) : i;
    union { short s[4]; uint64_t u; } p;
    p.s[0] = f2bf(v.x); p.s[1] = f2bf(v.y); p.s[2] = f2bf(v.z); p.s[3] = f2bf(v.w);
    *(uint64_t*)(dst + di) = p.u;
  } else if (b < NB_CONV + 128) {
    int flat = (b - NB_CONV) * 256 + threadIdx.x;
    int c = flat & (EE - 1);
    int h = (flat >> 10) & (HH - 1);
    int s = flat >> 14;
    const float* w = s ? wkr : wka;
    float acc = 0.f;
    #pragma unroll 8
    for (int d = 0; d < DD; ++d)
      acc += Wq[(size_t)(h * DD + d) * EE + c] * w[h * DD + d];
    u[flat] = acc;
  } else {
    int flat = (b - NB_CONV - 128) * 256 + threadIdx.x;
    int n = flat >> 5;
    int s = (flat >> 4) & 1;
    int h = flat & 15;
    const float* w = s ? wvr : wva;
    float acc = 0.f;
    #pragma unroll 8
    for (int d = 0; d < DD; ++d)
      acc += Wout[(size_t)n * EE + h * DD + d] * w[h * DD + d];
    W2[(size_t)n * KX + 1024 + s * 16 + h] = f2bf(acc);
  }
}

// ---- fused proj GEMM (blocks 0..383, 128x128 tiles) + qawker (384..2431) ----
// GEMM gld16 double-buffered, 1 barrier/step. z==2 stores C^T via swizzled LDS.
__global__ __launch_bounds__(256, 2) void projqaw(
    const short* __restrict__ Aall, const short* __restrict__ Ball,
    short* __restrict__ Call,
    int K, int aBatch, int bBatch, int cBatch,
    int ldc, int vTransZ, int ldcT, int scaleZ, float scaleVal,
    const float* __restrict__ Qf, const float* __restrict__ u,
    float* __restrict__ qaw)
{
  __shared__ __align__(16) short smem[16384];   // As[2][4096] | Bs[2][4096]
  int b = blockIdx.x;
  int t = threadIdx.x;

  if (b >= 384) {
    // ---- qawker branch: one q-row per block ----
    int i = b - 384;
    int h = t >> 4, seg = t & 15;
    const float* u0 = u + (size_t)h * EE;
    const float* u1 = u + (size_t)HH * EE + (size_t)h * EE;
    const float* q = Qf + (size_t)i * EE;
    float a0 = 0.f, a1 = 0.f;
    for (int cc = 0; cc < 64; ++cc) {
      int c = cc * 16 + seg;
      float qv = q[c];
      a0 += qv * u0[c];
      a1 += qv * u1[c];
    }
    #pragma unroll
    for (int m = 1; m < 16; m <<= 1) {
      a0 += __shfl_xor(a0, m);
      a1 += __shfl_xor(a1, m);
    }
    if (seg == 0) { qaw[i * 32 + h] = a0; qaw[i * 32 + 16 + h] = a1; }
    return;
  }

  // ---- GEMM branch: 128x128 tile ----
  short* As0 = smem;          // [2][4096]
  short* Bs0 = smem + 8192;   // [2][4096]
  int z = b / 128;
  int rem = b % 128;
  int n0 = (rem & 7) * 128, m0 = (rem >> 3) * 128;
  const short* A = Aall + (size_t)z * aBatch;
  const short* B = Ball + (size_t)z * bBatch;
  int lane = t & 63, w = t >> 6;
  int wm = w >> 1, wn = w & 1;
  int fr = lane & 15, g = lane >> 4, fo = g * 8;
  int lr = lane >> 2, lc = (lane & 3) * 8;
  const f32x4 vzero = {0.f, 0.f, 0.f, 0.f};
  f32x4 acc[4][4];
  #pragma unroll
  for (int i = 0; i < 4; ++i)
    #pragma unroll
    for (int j = 0; j < 4; ++j) acc[i][j] = vzero;

  int kTiles = K / 32;
  #pragma unroll
  for (int c = 0; c < 2; ++c) {
    int row = (w * 2 + c) * 16 + lr;
    gld16(&As0[(w * 2 + c) * 512], A + (size_t)(m0 + row) * K + lc);
    gld16(&Bs0[(w * 2 + c) * 512], B + (size_t)(n0 + row) * K + lc);
  }
  int cur = 0;
  for (int kt = 0; kt < kTiles; ++kt) {
    __syncthreads();
    if (kt + 1 < kTiles) {
      #pragma unroll
      for (int c = 0; c < 2; ++c) {
        int row = (w * 2 + c) * 16 + lr;
        gld16(&As0[(cur ^ 1) * 4096 + (w * 2 + c) * 512],
              A + (size_t)(m0 + row) * K + (kt + 1) * 32 + lc);
        gld16(&Bs0[(cur ^ 1) * 4096 + (w * 2 + c) * 512],
              B + (size_t)(n0 + row) * K + (kt + 1) * 32 + lc);
      }
    }
    short8 af[4], bf[4];
    #pragma unroll
    for (int i = 0; i < 4; ++i)
      af[i] = *(const short8*)&As0[cur * 4096 + (wm * 64 + i * 16 + fr) * 32 + fo];
    #pragma unroll
    for (int j = 0; j < 4; ++j)
      bf[j] = *(const short8*)&Bs0[cur * 4096 + (wn * 64 + j * 16 + fr) * 32 + fo];
    #pragma unroll
    for (int i = 0; i < 4; ++i)
      #pragma unroll
      for (int j = 0; j < 4; ++j)
        acc[i][j] = __builtin_amdgcn_mfma_f32_16x16x32_bf16(af[i], bf[j], acc[i][j], 0, 0, 0);
    cur ^= 1;
  }

  short* C = Call + (size_t)z * cBatch;
  bool doScale = (z == scaleZ);

  if (z == vTransZ) {
    // C^T via swizzled LDS transpose, two 64-row halves; coalesced 16B stores
    __syncthreads();
    for (int half = 0; half < 2; ++half) {
      if (wn == half) {
        #pragma unroll
        for (int i = 0; i < 4; ++i) {
          #pragma unroll
          for (int j = 0; j < 4; ++j) {
            int nl = j * 16 + fr;                  // 0..63 local n
            int chunk = wm * 16 + i * 4 + g;       // m/4, 0..31
            union { short s[4]; uint64_t u; } pk;
            #pragma unroll
            for (int r = 0; r < 4; ++r) {
              float val = acc[i][j][r];
              if (doScale) val *= scaleVal;
              pk.s[r] = f2bf(val);
            }
            *(uint64_t*)&smem[nl * 128 + (chunk ^ (nl & 15)) * 4] = pk.u;
          }
        }
      }
      __syncthreads();
      int row = t >> 2, seg = t & 3;               // 64 rows, 4 segs
      int nglob = n0 + half * 64 + row;
      #pragma unroll
      for (int cc = 0; cc < 4; ++cc) {
        int mc2 = seg * 4 + cc;                    // 16B chunk 0..15
        uint64_t lo = *(uint64_t*)&smem[row * 128 + ((mc2 * 2)     ^ (row & 15)) * 4];
        uint64_t hi = *(uint64_t*)&smem[row * 128 + ((mc2 * 2 + 1) ^ (row & 15)) * 4];
        union { uint64_t q[2]; int4 v; } st; st.q[0] = lo; st.q[1] = hi;
        *(int4*)(C + (size_t)nglob * ldcT + m0 + mc2 * 8) = st.v;
      }
      __syncthreads();
    }
    return;
  }

  #pragma unroll
  for (int i = 0; i < 4; ++i) {
    #pragma unroll
    for (int j = 0; j < 4; ++j) {
      int n = n0 + wn * 64 + j * 16 + fr;
      #pragma unroll
      for (int r = 0; r < 4; ++r) {
        int m = m0 + wm * 64 + i * 16 + g * 4 + r;
        float val = acc[i][j][r];
        if (doScale) val *= scaleVal;
        C[(size_t)m * ldc + n] = f2bf(val);
      }
    }
  }
}

// ---- final GEMM: 64x128 tile, gld16 double-buffered, fp32 out + bias ----
__global__ __launch_bounds__(256, 2) void gemm_bt(
    const short* __restrict__ A, const short* __restrict__ B,
    float* __restrict__ C, int K, int ldc, const float* __restrict__ bias)
{
  __shared__ __align__(16) short As[2][64 * 32];
  __shared__ __align__(16) short Bs[2][128 * 32];
  int m0 = blockIdx.y * 64, n0 = blockIdx.x * 128;
  int t = threadIdx.x;
  int lane = t & 63, w = t >> 6;
  int wm = w >> 1, wn = w & 1;
  int fr = lane & 15, fo = (lane >> 4) * 8;
  int lr = lane >> 2, lc = (lane & 3) * 8;
  const f32x4 vzero = {0.f, 0.f, 0.f, 0.f};
  f32x4 acc[2][4];
  #pragma unroll
  for (int i = 0; i < 2; ++i)
    #pragma unroll
    for (int j = 0; j < 4; ++j) acc[i][j] = vzero;

  int kTiles = K / 32;
  {
    int arow = w * 16 + lr;
    gld16(&As[0][w * 512], A + (size_t)(m0 + arow) * K + lc);
    #pragma unroll
    for (int c = 0; c < 2; ++c) {
      int brow = (w * 2 + c) * 16 + lr;
      gld16(&Bs[0][(w * 2 + c) * 512], B + (size_t)(n0 + brow) * K + lc);
    }
  }
  int cur = 0;
  for (int kt = 0; kt < kTiles; ++kt) {
    __syncthreads();
    if (kt + 1 < kTiles) {
      int arow = w * 16 + lr;
      gld16(&As[cur ^ 1][w * 512], A + (size_t)(m0 + arow) * K + (kt + 1) * 32 + lc);
      #pragma unroll
      for (int c = 0; c < 2; ++c) {
        int brow = (w * 2 + c) * 16 + lr;
        gld16(&Bs[cur ^ 1][(w * 2 + c) * 512],
              B + (size_t)(n0 + brow) * K + (kt + 1) * 32 + lc);
      }
    }
    short8 af[2], bfr[4];
    #pragma unroll
    for (int i = 0; i < 2; ++i)
      af[i] = *(const short8*)&As[cur][(wm * 32 + i * 16 + fr) * 32 + fo];
    #pragma unroll
    for (int j = 0; j < 4; ++j)
      bfr[j] = *(const short8*)&Bs[cur][(wn * 64 + j * 16 + fr) * 32 + fo];
    #pragma unroll
    for (int i = 0; i < 2; ++i)
      #pragma unroll
      for (int j = 0; j < 4; ++j)
        acc[i][j] = __builtin_amdgcn_mfma_f32_16x16x32_bf16(af[i], bfr[j], acc[i][j], 0, 0, 0);
    cur ^= 1;
  }

  int rb = (lane >> 4) * 4;
  #pragma unroll
  for (int i = 0; i < 2; ++i) {
    #pragma unroll
    for (int j = 0; j < 4; ++j) {
      int n = n0 + wn * 64 + j * 16 + fr;
      float bv = bias[n];
      #pragma unroll
      for (int r = 0; r < 4; ++r) {
        int m = m0 + wm * 32 + i * 16 + rb + r;
        C[(size_t)m * ldc + n] = acc[i][j][r] + bv;
      }
    }
  }
}

// ---- flash v11: flash10 + raw exp2 builtin + pointer-increment staging ----
__global__ __launch_bounds__(256, 4) void flash11(
    const short* __restrict__ qp, const short* __restrict__ kp,
    const short* __restrict__ vpT, const float* __restrict__ qaw,
    short* __restrict__ Obf, float* __restrict__ stats)
{
  __shared__ __align__(16) short lds[16384];
  int h = blockIdx.y;
  int q0 = blockIdx.x * 64;
  int split = blockIdx.z;
  int kbeg = split * 1024;
  int t = threadIdx.x, w = t >> 6, lane = t & 63;
  int g = lane >> 4, fr = lane & 15;
  int gi = q0 + w * 16 + fr;
  float gif = (float)gi;
  float g4f = (float)(4 * g);
  const f32x4 vzero = {0.f, 0.f, 0.f, 0.f};

  int srow = lane >> 3;
  int schunk = (lane & 7) ^ srow;
  const short* ksrcA = kp + (size_t)(kbeg + w * 16 + srow) * EE + h * 64 + schunk * 8;
  const short* ksrcB = ksrcA + (size_t)8 * EE;
  const short* vsrcA = vpT + (size_t)(h * 64 + w * 16 + srow) * LL + kbeg + schunk * 8;
  const short* vsrcB = vsrcA + (size_t)8 * LL;

  int fx = fr & 7;
  int kA0 = fr * 64 + ((g ^ fx) * 8);
  int kA1 = fr * 64 + (((g | 4) ^ fx) * 8);
  int g2 = g >> 1, gh = (g & 1) * 4;
  int vA[4];
  #pragma unroll
  for (int jt = 0; jt < 4; ++jt)
    vA[jt] = fr * 64 + (((2 * jt + g2) ^ fx) * 8) + gh;

  short8 qf[2];
  #pragma unroll
  for (int ks = 0; ks < 2; ++ks)
    qf[ks] = *(const short8*)(qp + (size_t)gi * EE + h * 64 + ks * 32 + g * 8);

  const float LOG2E = 1.4426950408889634f;
  const float sc = LOG2E / 32.f;
  float qa_s = qaw[gi * 32 + h] * sc;
  float qw_s = qaw[gi * 32 + 16 + h] * (sc / 5000.f);
  float qapw = qa_s + qw_s, qamw = qa_s - qw_s;

  float m2 = -1e30f, lsum = 0.f, SpA = 0.f, SrA = 0.f;
  f32x4 Oa[4];
  #pragma unroll
  for (int fc = 0; fc < 4; ++fc) Oa[fc] = vzero;

  // prologue: stage tile 0 into buffer 0
  gld16(lds + w * 1024,              ksrcA);
  gld16(lds + w * 1024 + 512,        ksrcB);
  gld16(lds + 4096 + w * 1024,       vsrcA);
  gld16(lds + 4096 + w * 1024 + 512, vsrcB);

  // running prefetch pointers (tile kt+1)
  const short* kpA = ksrcA + (size_t)64 * EE;
  const short* kpB = ksrcB + (size_t)64 * EE;
  const short* vpA = vsrcA + 64;
  const short* vpB = vsrcB + 64;

  int cur = 0;
  for (int kt = 0; kt < 16; ++kt) {
    int k0 = kbeg + kt * 64;
    float k0f = (float)k0;
    __syncthreads();

    if (kt < 15) {
      short* kb2 = lds + (cur ^ 1) * 8192;
      gld16(kb2 + w * 1024,              kpA);
      gld16(kb2 + w * 1024 + 512,        kpB);
      gld16(kb2 + 4096 + w * 1024,       vpA);
      gld16(kb2 + 4096 + w * 1024 + 512, vpB);
      kpA += (size_t)64 * EE; kpB += (size_t)64 * EE;
      vpA += 64; vpB += 64;
    }
    const short* kb = lds + cur * 8192;
    const short* vb = kb + 4096;

    f32x4 St[4];
    #pragma unroll
    for (int jt = 0; jt < 4; ++jt) {
      f32x4 a = vzero;
      a = __builtin_amdgcn_mfma_f32_16x16x32_bf16(
              *(const short8*)(kb + jt * 1024 + kA0), qf[0], a, 0, 0, 0);
      a = __builtin_amdgcn_mfma_f32_16x16x32_bf16(
              *(const short8*)(kb + jt * 1024 + kA1), qf[1], a, 0, 0, 0);
      St[jt] = a;
    }

    float pf[4][4];
    float tmv = -1e30f;
    if (k0 < q0) {
      float b4 = fmaf(g4f, qamw, k0f * qa_s + (gif - k0f) * qw_s);
      #pragma unroll
      for (int jt = 0; jt < 4; ++jt)
        #pragma unroll
        for (int r = 0; r < 4; ++r) {
          float e = St[jt][r] + fmaf((float)(jt * 16 + r), qamw, b4);
          pf[jt][r] = e;
          tmv = fmaxf(tmv, e);
        }
    } else if (k0 > q0) {
      float b4 = fmaf(g4f, qapw, k0f * qa_s + (k0f - gif) * qw_s);
      #pragma unroll
      for (int jt = 0; jt < 4; ++jt)
        #pragma unroll
        for (int r = 0; r < 4; ++r) {
          float e = St[jt][r] + fmaf((float)(jt * 16 + r), qapw, b4);
          pf[jt][r] = e;
          tmv = fmaxf(tmv, e);
        }
    } else {
      #pragma unroll
      for (int jt = 0; jt < 4; ++jt)
        #pragma unroll
        for (int r = 0; r < 4; ++r) {
          float jgf = k0f + g4f + (float)(jt * 16 + r);
          float e = St[jt][r] + jgf * qa_s + fabsf(gif - jgf) * qw_s;
          pf[jt][r] = e;
          tmv = fmaxf(tmv, e);
        }
    }
    tmv = fmaxf(tmv, __shfl_xor(tmv, 16));
    tmv = fmaxf(tmv, __shfl_xor(tmv, 32));

    if (__any(tmv > m2 + 8.f)) {
      float mn = fmaxf(m2, tmv);
      float alpha = EXP2(m2 - mn);
      m2 = mn;
      lsum *= alpha; SpA *= alpha; SrA *= alpha;
      #pragma unroll
      for (int r = 0; r < 4; ++r) {
        float alr = __shfl(alpha, ((lane >> 4) << 2) + r);
        #pragma unroll
        for (int fc = 0; fc < 4; ++fc) Oa[fc][r] *= alr;
      }
    }

    float Pt = 0.f, S1 = 0.f;
    #pragma unroll
    for (int jt = 0; jt < 4; ++jt)
      #pragma unroll
      for (int r = 0; r < 4; ++r) {
        float p = EXP2(pf[jt][r] - m2);
        pf[jt][r] = p;
        Pt += p;
        S1 = fmaf(p, (float)(jt * 16 + r), S1);
      }
    float jbase = k0f + g4f;
    lsum += Pt;
    SpA += fmaf(jbase, Pt, S1);
    if (k0 > q0)       SrA += fmaf(jbase - gif, Pt, S1);
    else if (k0 < q0)  SrA -= fmaf(jbase - gif, Pt, S1);
    else {
      #pragma unroll
      for (int jt = 0; jt < 4; ++jt)
        #pragma unroll
        for (int r = 0; r < 4; ++r)
          SrA = fmaf(pf[jt][r], fabsf(gif - (jbase + (float)(jt * 16 + r))), SrA);
    }

    s4v pa[4];
    #pragma unroll
    for (int jt = 0; jt < 4; ++jt) {
      int lo, hi;
      asm("v_cvt_pk_bf16_f32 %0, %1, %2" : "=v"(lo) : "v"(pf[jt][0]), "v"(pf[jt][1]));
      asm("v_cvt_pk_bf16_f32 %0, %1, %2" : "=v"(hi) : "v"(pf[jt][2]), "v"(pf[jt][3]));
      union { int i[2]; s4v s; } uu; uu.i[0] = lo; uu.i[1] = hi;
      pa[jt] = uu.s;
    }

    #pragma unroll
    for (int jt = 0; jt < 4; ++jt) {
      #pragma unroll
      for (int fc = 0; fc < 4; ++fc) {
        s4v vv = *(const s4v*)(vb + fc * 1024 + vA[jt]);
        Oa[fc] = MFMA16(pa[jt], vv, Oa[fc]);
      }
    }
    cur ^= 1;
  }

  lsum += __shfl_xor(lsum, 16); lsum += __shfl_xor(lsum, 32);
  SpA  += __shfl_xor(SpA, 16);  SpA  += __shfl_xor(SpA, 32);
  SrA  += __shfl_xor(SrA, 16);  SrA  += __shfl_xor(SrA, 32);

  size_t sb = (size_t)(split * HH + h) * LL;
  if (g == 0) {
    float4 s4 = {m2, lsum, SpA, SrA};
    *(float4*)&stats[(sb + q0 + w * 16 + fr) * 4] = s4;
  }

  float linv = 1.f / lsum;
  #pragma unroll
  for (int r = 0; r < 4; ++r) {
    int q = q0 + w * 16 + 4 * g + r;
    float il = __shfl(linv, 4 * g + r);
    union { short s[4]; uint64_t u; } pk;
    #pragma unroll
    for (int fc = 0; fc < 4; ++fc) pk.s[fc] = f2bf(Oa[fc][r] * il);
    *(uint64_t*)&Obf[(sb + q) * 64 + fr * 4] = pk.u;
  }
}

// ---- merge 2 splits (permuted Obf reads), emit X2 ----
__global__ __launch_bounds__(256) void merge2(const short* __restrict__ Obf,
                                              const float* __restrict__ stats,
                                              short* __restrict__ X2) {
  int q = blockIdx.x;
  int t = threadIdx.x;
  int h = t >> 4, ds = (t & 15) * 4;
  float4 s[2];
  #pragma unroll
  for (int i = 0; i < 2; ++i)
    s[i] = *(const float4*)&stats[((size_t)(i * HH + h) * LL + q) * 4];
  float m = fmaxf(s[0].x, s[1].x);
  float a[2], denom = 0.f;
  #pragma unroll
  for (int i = 0; i < 2; ++i) { a[i] = EXP2(s[i].x - m); denom += a[i] * s[i].y; }
  float invd = 1.f / denom;
  float acc[4] = {0.f, 0.f, 0.f, 0.f};
  #pragma unroll
  for (int i = 0; i < 2; ++i) {
    float wgt = a[i] * s[i].y * invd;
    const short* ob = &Obf[((size_t)(i * HH + h) * LL + q) * 64];
    #pragma unroll
    for (int e = 0; e < 4; ++e) {
      int d = ds + e;
      int pidx = (d & 15) * 4 + (d >> 4);
      acc[e] = fmaf(wgt, bf2f(ob[pidx]), acc[e]);
    }
  }
  union { short s[4]; uint64_t u; } pk;
  #pragma unroll
  for (int e = 0; e < 4; ++e) pk.s[e] = f2bf(acc[e]);
  *(uint64_t*)&X2[(size_t)q * KX + h * 64 + ds] = pk.u;

  if (t < 32) {
    int hh = t & 15;
    float4 ts[2];
    float mm = -1e30f;
    #pragma unroll
    for (int i = 0; i < 2; ++i) {
      ts[i] = *(const float4*)&stats[((size_t)(i * HH + hh) * LL + q) * 4];
      mm = fmaxf(mm, ts[i].x);
    }
    float num = 0.f, den = 0.f;
    #pragma unroll
    for (int i = 0; i < 2; ++i) {
      float ai = EXP2(ts[i].x - mm);
      den += ai * ts[i].y;
      num += ai * ((t < 16) ? ts[i].z : ts[i].w);
    }
    float val = num / den;
    if (t >= 16) val *= (1.f / 5000.f);
    X2[(size_t)q * KX + 1024 + (t < 16 ? hh : 16 + hh)] = f2bf(val);
  }
}

extern "C" void kernel_launch(void* const* d_in, const int* in_sizes, int n_in,
                              void* d_out, int out_size, void* d_ws, size_t ws_size,
                              hipStream_t stream) {
  const float* V    = (const float*)d_in[0];
  const float* Kin  = (const float*)d_in[1];
  const float* Q    = (const float*)d_in[2];
  const float* Wq   = (const float*)d_in[4];
  const float* Wk   = (const float*)d_in[5];
  const float* Wv   = (const float*)d_in[6];
  const float* Wkr  = (const float*)d_in[7];
  const float* Wvr  = (const float*)d_in[8];
  const float* Wka  = (const float*)d_in[9];
  const float* Wva  = (const float*)d_in[10];
  const float* Wout = (const float*)d_in[11];
  const float* bout = (const float*)d_in[12];

  char* ws = (char*)d_ws;
  size_t off = 0;
  auto alloc = [&](size_t bytes) -> void* {
    void* p = ws + off;
    off = (off + bytes + 255) & ~(size_t)255;
    return p;
  };
  short* Qb  = (short*)alloc((size_t)LL * EE * 2);   // ┐ overlay (18.87 MB):
  short* Kb  = (short*)alloc((size_t)LL * EE * 2);   // │ dead after proj gemm;
  short* Vb  = (short*)alloc((size_t)LL * EE * 2);   // │ reused as Obf(8MB)+stats(1MB)
  short* Wqb = (short*)alloc((size_t)EE * EE * 2);   // │
  short* Wkb = (short*)alloc((size_t)EE * EE * 2);   // │
  short* Wvb = (short*)alloc((size_t)EE * EE * 2);   // ┘
  short* qp  = (short*)alloc((size_t)LL * EE * 2);
  short* kp  = (short*)alloc((size_t)LL * EE * 2);
  short* vpT = (short*)alloc((size_t)EE * LL * 2);
  short* W2  = (short*)alloc((size_t)EE * KX * 2);
  short* X2  = (short*)alloc((size_t)LL * KX * 2);
  float* u   = (float*)alloc((size_t)2 * HH * EE * 4);
  float* qaw = (float*)alloc((size_t)LL * 32 * 4);
  short* Obf   = Qb;                                             // 8,388,608 B
  float* stats = (float*)((char*)Qb + (size_t)16777216);         // 1,048,576 B
  (void)in_sizes; (void)n_in; (void)out_size; (void)ws_size;

  const float sc = 1.4426950408889634f / 32.f;

  // 1) bf16 converts + uker + mrelker, one launch
  convfused<<<NB_CONV + 256, 256, 0, stream>>>(
      Q, Kin, V, Wq, Wk, Wv, Wout, Wka, Wkr, Wva, Wvr,
      Qb, Kb, Vb, Wqb, Wkb, Wvb, W2, u);

  // 2) fused projections (128x128 tiles, 384 blocks) + qaw (2048 blocks)
  projqaw<<<384 + LL, 256, 0, stream>>>(Qb, Wqb, qp, EE,
                                        LL * EE, EE * EE, LL * EE,
                                        EE, /*vTransZ=*/2, /*ldcT=*/LL,
                                        /*scaleZ=*/0, sc,
                                        Q, u, qaw);

  // 3) split-K(2) flash (gld_lds dbuf + swizzle + raw exp2) -> partials
  flash11<<<dim3(LL / 64, HH, 2), 256, 0, stream>>>(qp, kp, vpT, qaw, Obf, stats);

  // 4) merge 2 splits -> X2
  merge2<<<LL, 256, 0, stream>>>(Obf, stats, X2);

  // 5) final: d_out = X2 @ W2^T + b_out (dbuf 64x128 tile -> 256 blocks)
  dim3 go(EE / 128, LL / 64);
  gemm_bt<<<go, 256, 0, stream>>>(X2, W2, (float*)d_out, KX, EE, bout);
}